// Round 16
// baseline (296.974 us; speedup 1.0000x reference)
//
#include <hip/hip_runtime.h>
#include <hip/hip_cooperative_groups.h>
#include <math.h>

namespace cg = cooperative_groups;

#define NB 512
#define NN 64
#define TL 657
#define LV1 328
#define LV2 164
#define LV3 82
#define LV4 41
#define HID 82
#define ST 66
#define NGB 32     // graph slice blocks (16 per graph)

// workspace byte offsets
#define WS_M      0          // 2*4096 f32
#define WS_ACC    32768      // 512 doubles
#define WS_SMEAN  36864      // 512*64 f32 -> ends 167936
#define WS_SMAX   167936     // -> ends 299008
#define WS_CSP    299008     // 1024*657 f32 -> ends 2990080
#define WS_CMP    2990080    // 1024*657 f32 -> ends 5681152
#define WS_CATT   5681152    // 512*657 f32 -> ends 7026688
#define WS_DELTA  7026688    // 512*64*41 f32 -> ends 12400640

#define ACC_Y1 0
#define ACC_Y2 64
#define ACC_O1 80

__device__ __forceinline__ float sigmoidf_(float v){ return 1.0f/(1.0f+expf(-v)); }

__device__ __forceinline__ void wav_level(float* __restrict__ dst, const float* __restrict__ src,
                                          int outL, int inL, int lane){
  const float DLO[8] = {0.23037781330885523f, 0.7148465705525415f, 0.6308807679295904f,
                        -0.02798376941698385f, -0.18703481171888114f, 0.030841381835986965f,
                        0.032883011666982945f, -0.010597401784997278f};
  for (int k=lane; k<outL; k+=64){
    int i0 = 2*k - 3;
    float a = 0.f;
    #pragma unroll
    for (int j=0;j<8;j++){
      int idx = i0 + j;
      idx = (idx < 0) ? idx + inL : ((idx >= inL) ? idx - inL : idx);
      a += src[idx]*DLO[j];
    }
    dst[k] = a;
  }
}

// ---------------- k_stats: grid 32+1024, 512 thr ----------------
__global__ __launch_bounds__(512) void k_stats(
    const float* __restrict__ x,
    const float* __restrict__ lgw, const float* __restrict__ gmask,
    const float* __restrict__ tril, const int* __restrict__ edges,
    float* __restrict__ csum_p, float* __restrict__ cmax_p,
    float* __restrict__ Mout, double* __restrict__ acc)
{
  __shared__ float smem[8848];
  __shared__ float deg[64], hsv[64], dinv[64], wself[64];
  int tid = threadIdx.x;
  int bid = blockIdx.x;

  if (bid < NGB){
    int g  = bid >> 4;
    int s4 = (bid & 15) * 4;
    float* Wbuf = smem;
    float* Amat = smem + 4096;
    float* Rc   = smem + 8320;
    float* Rn   = smem + 8584;
    if (bid==0 && tid<512) acc[tid]=0.0;
    for (int e=tid;e<4096;e+=512){
      float w;
      if (g==0) w = lgw[e];
      else {
        int i=e>>6, j=e&63;
        int aa = (i>j)? i:j, bb = (i>j)? j:i;
        w = tril[aa*(aa+1)/2 + bb] * gmask[e];
      }
      Wbuf[e] = w;
    }
    for (int i=tid;i<NN*ST;i+=512) Amat[i] = 0.f;
    if (tid<64){ deg[tid]=0.f; hsv[tid]=0.f; }
    __syncthreads();
    {
      int e0 = tid*8;
      int runr = edges[e0];
      float runv = 0.f;
      #pragma unroll
      for (int i=0;i<8;i++){
        int e = e0+i;
        int r = edges[e];
        int c = edges[4096+e];
        float w = Wbuf[e];
        if (r != runr){ atomicAdd(&deg[runr], runv); runr = r; runv = 0.f; }
        runv += fabsf(w);
        if (r == c) hsv[r] = 1.f;
      }
      atomicAdd(&deg[runr], runv);
    }
    __syncthreads();
    if (tid<64){
      float w_ = (hsv[tid] > 0.f) ? 0.f : 1.f;
      float d = deg[tid] + w_;
      dinv[tid] = (d > 0.f) ? rsqrtf(d) : 0.f;
      wself[tid] = w_;
    }
    __syncthreads();
    for (int e=tid;e<4096;e+=512){
      int r = edges[e], c = edges[4096+e];
      float nm = dinv[r]*Wbuf[e]*dinv[c];
      atomicAdd(&Amat[c*ST+r], nm);
    }
    __syncthreads();
    if (tid<64) Amat[tid*ST+tid] += dinv[tid]*wself[tid]*dinv[tid];
    __syncthreads();
    if (tid < 256){
      int r = tid>>6, c = tid&63;
      Rc[r*ST+c] = Amat[(s4+r)*ST+c];
    }
    __syncthreads();
    #pragma unroll
    for (int it=0; it<4; it++){
      if (tid < 256){
        int r = tid>>6, c = tid&63;
        const float* rr = &Rc[r*ST];
        float a0=0.f, a1=0.f;
        #pragma unroll 8
        for (int k=0;k<64;k+=2){
          a0 += rr[k]  *Amat[k*ST+c];
          a1 += rr[k+1]*Amat[(k+1)*ST+c];
        }
        Rn[r*ST+c] = a0+a1;
      }
      __syncthreads();
      float* t = Rc; Rc = Rn; Rn = t;
    }
    if (tid < 256){
      int r = tid>>6, c = tid&63;
      Mout[g*4096 + (s4+r)*64 + c] = Rc[r*ST+c];
    }
    return;
  }

  int sid = bid - NGB;
  int b = sid >> 1, split = sid & 1;
  const float4* xb4 = (const float4*)(x + (size_t)b*NN*TL) + (size_t)split*8*657;
  int f0 = tid;
  int f1 = 512 + tid;
  bool has1 = (f1 < 657);
  float4 S0 = make_float4(0.f,0.f,0.f,0.f);
  float4 M0 = make_float4(-INFINITY,-INFINITY,-INFINITY,-INFINITY);
  float4 S1 = S0, M1 = M0;
  #pragma unroll
  for (int g=0; g<8; ++g){
    float4 v = xb4[g*657 + f0];
    S0.x += v.x; S0.y += v.y; S0.z += v.z; S0.w += v.w;
    M0.x = fmaxf(M0.x, v.x); M0.y = fmaxf(M0.y, v.y);
    M0.z = fmaxf(M0.z, v.z); M0.w = fmaxf(M0.w, v.w);
    if (has1){
      float4 w = xb4[g*657 + f1];
      S1.x += w.x; S1.y += w.y; S1.z += w.z; S1.w += w.w;
      M1.x = fmaxf(M1.x, w.x); M1.y = fmaxf(M1.y, w.y);
      M1.z = fmaxf(M1.z, w.z); M1.w = fmaxf(M1.w, w.w);
    }
  }
  float* Sf = smem;
  float* Mf = smem + 2628;
  *(float4*)&Sf[4*f0] = S0;
  *(float4*)&Mf[4*f0] = M0;
  if (has1){
    *(float4*)&Sf[4*f1] = S1;
    *(float4*)&Mf[4*f1] = M1;
  }
  __syncthreads();
  for (int c=tid; c<TL; c+=512){
    float s = (Sf[c] + Sf[c+657]) + (Sf[c+1314] + Sf[c+1971]);
    float m = fmaxf(fmaxf(Mf[c], Mf[c+657]), fmaxf(Mf[c+1314], Mf[c+1971]));
    csum_p[(size_t)sid*TL + c] = s;
    cmax_p[(size_t)sid*TL + c] = m;
  }
}

// ---------------- k_mlp ----------------
__global__ __launch_bounds__(512) void k_mlp(
    const float* __restrict__ csum_p, const float* __restrict__ cmax_p,
    const float* __restrict__ fc1, const float* __restrict__ fc2,
    float* __restrict__ catt_g)
{
  __shared__ float cs[660], cm[660], h[84];
  int tid = threadIdx.x, b = blockIdx.x;
  int wv = tid>>6, lane = tid&63;
  const float* s0 = csum_p + (size_t)(2*b  )*TL;
  const float* s1 = csum_p + (size_t)(2*b+1)*TL;
  const float* m0 = cmax_p + (size_t)(2*b  )*TL;
  const float* m1 = cmax_p + (size_t)(2*b+1)*TL;
  for (int c=tid; c<TL; c+=512){
    cs[c] = s0[c] + s1[c];
    cm[c] = fmaxf(m0[c], m1[c]);
  }
  __syncthreads();
  for (int o=wv; o<HID; o+=8){
    const float* fr = fc1 + (size_t)o*TL;
    float a = 0.f, bm = 0.f;
    #pragma unroll
    for (int i=0;i<11;i++){
      int c = lane + 64*i;
      if (c < TL){
        float f = fr[c];
        a += f*cs[c]; bm += f*cm[c];
      }
    }
    #pragma unroll
    for (int off=32;off;off>>=1){
      a  += __shfl_xor(a,off);
      bm += __shfl_xor(bm,off);
    }
    if (lane==0)
      h[o] = fmaxf(a*(1.0f/64.0f),0.f) + fmaxf(bm,0.f);
  }
  __syncthreads();
  for (int c=tid; c<TL; c+=512){
    const float2* fr = (const float2*)(fc2 + (size_t)c*HID);
    float a0=0.f, a1=0.f;
    #pragma unroll
    for (int u2=0;u2<41;u2++){
      float2 v = fr[u2];
      a0 += v.x*h[2*u2]; a1 += v.y*h[2*u2+1];
    }
    catt_g[(size_t)b*TL + c] = sigmoidf_(a0+a1);
  }
}

// ---------------- k_wav: grid (512,16), float4 staging ----------------
__global__ __launch_bounds__(256) void k_wav(
    const float* __restrict__ x, const float* __restrict__ catt_g,
    float* __restrict__ delta, float* __restrict__ smean, float* __restrict__ smax)
{
  __shared__ float catt[660];
  __shared__ float buf[2664];
  __shared__ float o1b[4][332];
  __shared__ float o2b[4][166];
  __shared__ float o3b[4][84];
  int tid = threadIdx.x, b = blockIdx.x, q = blockIdx.y;
  for (int i=tid;i<TL;i+=256) catt[i] = catt_g[(size_t)b*TL + i];
  __syncthreads();
  const float4* g4 = (const float4*)(x + ((size_t)b*NN + q*4)*TL);
  for (int f=tid; f<657; f+=256){
    float4 v = g4[f];
    int e = 4*f;
    if (f==164 || f==328 || f==492){
      float ev[4] = {v.x, v.y, v.z, v.w};
      #pragma unroll
      for (int j=0;j<4;j++){
        int ee = e+j;
        int r = (ee>=657) + (ee>=1314) + (ee>=1971);
        buf[ee + 12*r] = ev[j];
      }
    } else {
      int r = (e>=657) + (e>=1314) + (e>=1971);
      *(float4*)&buf[e + 12*r] = v;
    }
  }
  __syncthreads();
  int wv = tid>>6, lane = tid&63;
  int n = q*4 + wv;
  float* y = &buf[669*wv];
  float ls = 0.f, lm = -INFINITY;
  #pragma unroll
  for (int i=0;i<11;i++){
    int t = lane + 64*i;
    if (t < TL){
      float vv = y[t]*catt[t];
      y[t] = vv; ls += vv; lm = fmaxf(lm,vv);
    }
  }
  #pragma unroll
  for (int off=32;off;off>>=1){
    ls += __shfl_xor(ls,off);
    lm = fmaxf(lm, __shfl_xor(lm,off));
  }
  if (lane==0){ smean[b*NN+n] = ls*(1.0f/657.0f); smax[b*NN+n] = lm; }
  wav_level(o1b[wv], y,       LV1, TL,  lane);
  wav_level(o2b[wv], o1b[wv], LV2, LV1, lane);
  wav_level(o3b[wv], o2b[wv], LV3, LV2, lane);
  if (lane < LV4){
    const float DLO[8] = {0.23037781330885523f, 0.7148465705525415f, 0.6308807679295904f,
                          -0.02798376941698385f, -0.18703481171888114f, 0.030841381835986965f,
                          0.032883011666982945f, -0.010597401784997278f};
    int i0 = 2*lane - 3;
    float a = 0.f;
    #pragma unroll
    for (int j=0;j<8;j++){
      int idx = i0 + j;
      idx = (idx < 0) ? idx + LV3 : ((idx >= LV3) ? idx - LV3 : idx);
      a += o3b[wv][idx]*DLO[j];
    }
    delta[((size_t)b*NN + n)*LV4 + lane] = a;
  }
}

// ---------------- k_tail: cooperative gcn1 -> gcn2 -> featcls -> cls2 ----------------
__global__ __launch_bounds__(256) void k_tail(
  const float* __restrict__ delta, const float* __restrict__ Mmat,
  const float* __restrict__ smean, const float* __restrict__ smax,
  const float* __restrict__ saw,
  const float* __restrict__ ldW, const float* __restrict__ ldb,
  const float* __restrict__ dW, const float* __restrict__ db2,
  const float* __restrict__ ldg, const float* __restrict__ ldbe,
  const float* __restrict__ dg, const float* __restrict__ dbe,
  const float* __restrict__ ld1W, const float* __restrict__ ld1b,
  const float* __restrict__ d1W, const float* __restrict__ d1b,
  const float* __restrict__ ld1g, const float* __restrict__ ld1be,
  const float* __restrict__ d1g, const float* __restrict__ d1be,
  const float* __restrict__ cW1, const float* __restrict__ cb1,
  const float* __restrict__ cgam, const float* __restrict__ cbet,
  const float* __restrict__ cW2, const float* __restrict__ cb2,
  double* __restrict__ acc, float* __restrict__ out)
{
  cg::grid_group grid = cg::this_grid();
  __shared__ float Yl[NN*32];     // Y1 tile (persists P1->P2)
  __shared__ float Y2l[NN*8];     // Y2 tile (persists P2->P3)
  __shared__ float o1l[32];       // out1 (persists P3->P4)
  __shared__ float Dl[NN*LV4];
  __shared__ float Mm[4096];
  __shared__ float Tt[1024];      // T (gcn1), T2 (gcn2), f[128] (featcls), v[32] (cls2)
  __shared__ float Wl[16*LV4];
  __shared__ float satt[NN];
  __shared__ float scl[32], sht[32];
  __shared__ double red[256];
  int tid = threadIdx.x, b = blockIdx.x;

  // ---- P1: gcn1 ----
  if (tid < NN){
    float a = 0.f;
    #pragma unroll
    for (int kw=0;kw<7;kw++){
      int w = tid + kw - 3;
      if (0<=w && w<NN) a += smean[b*NN+w]*saw[21+kw] + smax[b*NN+w]*saw[70+kw];
    }
    satt[tid] = sigmoidf_(a);
  }
  __syncthreads();
  const float* ds = delta + (size_t)b*NN*LV4;
  for (int i=tid;i<NN*LV4;i+=256) Dl[i] = ds[i]*satt[i/LV4];
  for (int g=0; g<2; g++){
    const float* Ws = g ? dW : ldW;
    const float* bs = g ? db2 : ldb;
    for (int i=tid;i<16*LV4;i+=256) Wl[i]=Ws[i];
    const float4* Mm4 = (const float4*)(Mmat + g*4096);
    for (int i=tid;i<1024;i+=256) *(float4*)&Mm[4*i] = Mm4[i];
    __syncthreads();
    for (int e=tid;e<NN*16;e+=256){
      int n=e>>4, o=e&15;
      const float* dr=&Dl[n*LV4];
      const float* wr=&Wl[o*LV4];
      float a=0.f;
      #pragma unroll 8
      for (int c=0;c<LV4;c++) a += dr[c]*wr[c];
      Tt[e]=a;
    }
    __syncthreads();
    float bias = bs[tid&15];
    float ps=0.f, pq=0.f;
    for (int m=0;m<4;m++){
      int e=tid+256*m;
      int n=e>>4, o=e&15;
      float a=bias;
      #pragma unroll 8
      for (int k=0;k<64;k++) a += Mm[n*64+k]*Tt[k*16+o];
      Yl[n*32 + g*16 + o] = a;
      ps += a; pq += a*a;
    }
    red[tid]=(double)ps;
    __syncthreads();
    if (tid<16){ double t=0; for (int r=tid;r<256;r+=16) t+=red[r]; atomicAdd(&acc[ACC_Y1+g*32+tid], t); }
    __syncthreads();
    red[tid]=(double)pq;
    __syncthreads();
    if (tid<16){ double t=0; for (int r=tid;r<256;r+=16) t+=red[r]; atomicAdd(&acc[ACC_Y1+g*32+16+tid], t); }
    __syncthreads();
  }

  grid.sync();

  // ---- P2: gcn2 ----
  if (tid<32){
    int g=tid>>4, o=tid&15;
    double s=acc[ACC_Y1+g*32+o], q=acc[ACC_Y1+g*32+16+o];
    double mean=s/32768.0;
    double var=q/32768.0 - mean*mean;
    float gam = g? dg[o] : ldg[o];
    float bet = g? dbe[o] : ldbe[o];
    float sc = gam * rsqrtf((float)var + 1e-5f);
    scl[tid]=sc; sht[tid]=bet - (float)mean*sc;
  }
  __syncthreads();
  for (int i=tid;i<NN*32;i+=256){ int c=i&31; Yl[i]=Yl[i]*scl[c]+sht[c]; }
  __syncthreads();
  for (int e=tid;e<NN*8;e+=256){
    int n=e>>3, c=e&7, g=c>>2, p=c&3;
    const float* w = (g? d1W : ld1W) + p*16;
    const float* yr = &Yl[n*32 + g*16];
    float a=0.f;
    #pragma unroll
    for (int o=0;o<16;o++) a += yr[o]*w[o];
    Tt[e]=a;   // T2
  }
  __syncthreads();
  for (int g=0; g<2; g++){
    const float4* Mm4 = (const float4*)(Mmat + g*4096);
    for (int i=tid;i<1024;i+=256) *(float4*)&Mm[4*i] = Mm4[i];
    __syncthreads();
    int n = tid>>2, p = tid&3, c = g*4+p;
    float a = g? d1b[p] : ld1b[p];
    const float* mr = &Mm[n*64];
    #pragma unroll 8
    for (int k=0;k<64;k++) a += mr[k]*Tt[k*8+c];
    Y2l[n*8+c] = a;
    red[tid]=(double)a;
    __syncthreads();
    if (tid<4){ double t=0; for (int r=tid;r<256;r+=4) t+=red[r]; atomicAdd(&acc[ACC_Y2+g*8+tid], t); }
    __syncthreads();
    red[tid]=(double)(a*a);
    __syncthreads();
    if (tid<4){ double t=0; for (int r=tid;r<256;r+=4) t+=red[r]; atomicAdd(&acc[ACC_Y2+g*8+4+tid], t); }
    __syncthreads();
  }

  grid.sync();

  // ---- P3: featcls ----
  if (tid<8){
    int g=tid>>2, p=tid&3;
    double s=acc[ACC_Y2+g*8+p], q=acc[ACC_Y2+g*8+4+p];
    double mean=s/32768.0;
    double var=q/32768.0-mean*mean;
    float gam = g? d1g[p]:ld1g[p];
    float bet = g? d1be[p]:ld1be[p];
    float sc = gam*rsqrtf((float)var+1e-5f);
    scl[tid]=sc; sht[tid]=bet-(float)mean*sc;
  }
  __syncthreads();
  if (tid < NN){
    const float* yr = &Y2l[tid*8];
    float lf=0.f, gf=0.f;
    #pragma unroll
    for (int p=0;p<4;p++){
      lf += yr[p]*scl[p]+sht[p];
      gf += yr[4+p]*scl[4+p]+sht[4+p];
    }
    Tt[2*tid]   = lf*0.25f;   // f[128]
    Tt[2*tid+1] = gf*0.25f;
  }
  __syncthreads();
  if (tid<32){
    const float* w = cW1 + tid*128;
    float a = cb1[tid];
    #pragma unroll 4
    for (int m=0;m<128;m++) a += w[m]*Tt[m];
    o1l[tid]=a;
    atomicAdd(&acc[ACC_O1+tid], (double)a);
    atomicAdd(&acc[ACC_O1+32+tid], (double)(a*a));
  }

  grid.sync();

  // ---- P4: cls2 ----
  if (tid<32){
    double s=acc[ACC_O1+tid], q=acc[ACC_O1+32+tid];
    double mean=s/512.0;
    double var=q/512.0-mean*mean;
    float sc=cgam[tid]*rsqrtf((float)var+1e-5f);
    float sh=cbet[tid]-(float)mean*sc;
    Tt[tid]=o1l[tid]*sc+sh;   // v[32]
  }
  __syncthreads();
  if (tid<2){
    const float* w=cW2+tid*32;
    float a=cb2[tid];
    #pragma unroll
    for (int j=0;j<32;j++) a += w[j]*Tt[j];
    Tt[64+tid]=a;
  }
  __syncthreads();
  if (tid<2){
    float m=fmaxf(Tt[64],Tt[65]);
    float l=m+logf(expf(Tt[64]-m)+expf(Tt[65]-m));
    out[b*2+tid]=Tt[64+tid]-l;
  }
}

extern "C" void kernel_launch(void* const* d_in, const int* in_sizes, int n_in,
                              void* d_out, int out_size, void* d_ws, size_t ws_size,
                              hipStream_t stream) {
  (void)in_sizes; (void)n_in; (void)out_size; (void)ws_size;
  const float* x     = (const float*)d_in[0];
  const float* lgw   = (const float*)d_in[1];
  const float* gmask = (const float*)d_in[2];
  const float* fc1   = (const float*)d_in[3];
  const float* fc2   = (const float*)d_in[4];
  const float* saw   = (const float*)d_in[5];
  const float* tril  = (const float*)d_in[6];
  const float* ldW   = (const float*)d_in[7];
  const float* ldb   = (const float*)d_in[8];
  const float* ldg   = (const float*)d_in[9];
  const float* ldbe  = (const float*)d_in[10];
  const float* ld1W  = (const float*)d_in[11];
  const float* ld1b  = (const float*)d_in[12];
  const float* ld1g  = (const float*)d_in[13];
  const float* ld1be = (const float*)d_in[14];
  const float* dW    = (const float*)d_in[15];
  const float* db2   = (const float*)d_in[16];
  const float* dg    = (const float*)d_in[17];
  const float* dbe   = (const float*)d_in[18];
  const float* d1W   = (const float*)d_in[19];
  const float* d1b   = (const float*)d_in[20];
  const float* d1g   = (const float*)d_in[21];
  const float* d1be  = (const float*)d_in[22];
  const float* cW1   = (const float*)d_in[23];
  const float* cb1   = (const float*)d_in[24];
  const float* cgam  = (const float*)d_in[25];
  const float* cbet  = (const float*)d_in[26];
  const float* cW2   = (const float*)d_in[27];
  const float* cb2   = (const float*)d_in[28];
  const int*   edges = (const int*)d_in[29];

  char* ws = (char*)d_ws;
  float*  M      = (float*)(ws + WS_M);
  double* acc    = (double*)(ws + WS_ACC);
  float*  smean  = (float*)(ws + WS_SMEAN);
  float*  smax   = (float*)(ws + WS_SMAX);
  float*  csum_p = (float*)(ws + WS_CSP);
  float*  cmax_p = (float*)(ws + WS_CMP);
  float*  catt   = (float*)(ws + WS_CATT);
  float*  delta  = (float*)(ws + WS_DELTA);
  float*  out    = (float*)d_out;

  k_stats<<<NGB + 2*NB, 512, 0, stream>>>(x, lgw, gmask, tril, edges,
                                          csum_p, cmax_p, M, acc);
  k_mlp<<<NB, 512, 0, stream>>>(csum_p, cmax_p, fc1, fc2, catt);
  k_wav<<<dim3(NB, 16), 256, 0, stream>>>(x, catt, delta, smean, smax);

  void* args[] = {
    (void*)&delta, (void*)&M, (void*)&smean, (void*)&smax, (void*)&saw,
    (void*)&ldW, (void*)&ldb, (void*)&dW, (void*)&db2,
    (void*)&ldg, (void*)&ldbe, (void*)&dg, (void*)&dbe,
    (void*)&ld1W, (void*)&ld1b, (void*)&d1W, (void*)&d1b,
    (void*)&ld1g, (void*)&ld1be, (void*)&d1g, (void*)&d1be,
    (void*)&cW1, (void*)&cb1, (void*)&cgam, (void*)&cbet,
    (void*)&cW2, (void*)&cb2, (void*)&acc, (void*)&out
  };
  hipLaunchCooperativeKernel((void*)k_tail, dim3(NB), dim3(256), args, 0, stream);
}